// Round 1
// baseline (779.732 us; speedup 1.0000x reference)
//
#include <hip/hip_runtime.h>
#include <cmath>

#define N_F    2000
#define N_ALL  3000
#define N_SRC  2500   // src nodes occupy [0, 2500)
#define OUT0   2500   // output nodes occupy [2500, 3000)
#define C      8
#define H      16000  // N_F * C
#define B      256
#define E      47000
#define LAYERS 10
#define EPSF   1e-5f
#define CHK    64
#define SB     250    // stat blocks
#define SR     64     // rows per stat block (SB*SR == H)

// ---------------- CSR build ----------------

__global__ void k_zero(int* cnt_dst, int* cnt_src) {
    int tid = threadIdx.x;
    for (int i = tid; i < N_ALL; i += 1024) { cnt_dst[i] = 0; cnt_src[i] = 0; }
}

__global__ void k_count(const int* __restrict__ src, const int* __restrict__ dst,
                        int* cnt_dst, int* cnt_src) {
    int e = blockIdx.x * 256 + threadIdx.x;
    if (e < E) {
        atomicAdd(&cnt_dst[dst[e]], 1);
        atomicAdd(&cnt_src[src[e]], 1);
    }
}

// one block per array: block 0 scans dst counts, block 1 scans src counts
__global__ void k_scan(const int* cnt_dst, const int* cnt_src,
                       int* rs_dst, int* rs_src, int* cur_dst, int* cur_src) {
    const int* cnt = (blockIdx.x == 0) ? cnt_dst : cnt_src;
    int* rs  = (blockIdx.x == 0) ? rs_dst : rs_src;
    int* cur = (blockIdx.x == 0) ? cur_dst : cur_src;
    __shared__ int buf[1024];
    __shared__ int carry;
    int tid = threadIdx.x;
    if (tid == 0) carry = 0;
    __syncthreads();
    for (int base = 0; base < N_ALL; base += 1024) {
        int i = base + tid;
        int v = (i < N_ALL) ? cnt[i] : 0;
        buf[tid] = v;
        __syncthreads();
        for (int off = 1; off < 1024; off <<= 1) {
            int t = (tid >= off) ? buf[tid - off] : 0;
            __syncthreads();
            buf[tid] += t;
            __syncthreads();
        }
        int excl = carry + buf[tid] - v;
        if (i < N_ALL) { rs[i] = excl; cur[i] = excl; }
        int tot = buf[1023];
        __syncthreads();
        if (tid == 0) carry += tot;
        __syncthreads();
    }
    if (tid == 0) rs[N_ALL] = carry;
}

__global__ void k_fill(const int* __restrict__ src, const int* __restrict__ dst,
                       int* cur_dst, int* cur_src, int* csr_dst, int* csr_src) {
    int e = blockIdx.x * 256 + threadIdx.x;
    if (e < E) {
        int p = atomicAdd(&cur_dst[dst[e]], 1); csr_dst[p] = e;
        int q = atomicAdd(&cur_src[src[e]], 1); csr_src[q] = e;
    }
}

// ---------------- init ----------------

// x (B, N_ALL) -> xT (N_ALL, B)
__global__ void k_xT(const float* __restrict__ x, float* __restrict__ xT) {
    __shared__ float t[32][33];
    int tx = threadIdx.x, ty = threadIdx.y;
    int n = blockIdx.x * 32 + tx, b = blockIdx.y * 32 + ty;
    if (n < N_ALL) t[ty][tx] = x[b * N_ALL + n];
    __syncthreads();
    int n2 = blockIdx.x * 32 + ty, b2 = blockIdx.y * 32 + tx;
    if (n2 < N_ALL) xT[n2 * B + b2] = t[tx][ty];
}

// xe[e][b] = xT[src[e]][b]
__global__ void k_init(const int* __restrict__ src, const float* __restrict__ xT,
                       float* __restrict__ xe) {
    int tid = threadIdx.x;
    int e0 = blockIdx.x * 16;
    for (int k = 0; k < 16; ++k) {
        int e = e0 + k;
        if (e < E) {
            int s = src[e];
            xe[e * B + tid] = xT[s * B + tid];
        }
    }
}

// ---------------- per-layer ----------------

// h[(n*C+c)*B + b] = sum_{e in csr_dst[n]} xe[e][b] * w1[e][c]   (n < N_F)
__global__ void k_hid(const float* __restrict__ xe, const float* __restrict__ w1,
                      const int* __restrict__ rs_dst, const int* __restrict__ csr_dst,
                      float* __restrict__ h) {
    int n = blockIdx.x, tid = threadIdx.x;
    int beg = rs_dst[n], end = rs_dst[n + 1];
    float acc[C] = {0.f, 0.f, 0.f, 0.f, 0.f, 0.f, 0.f, 0.f};
    __shared__ int   eid[CHK];
    __shared__ float w1s[CHK][C];
    for (int cb = beg; cb < end; cb += CHK) {
        int m = min(CHK, end - cb);
        if (tid < m) eid[tid] = csr_dst[cb + tid];
        __syncthreads();
        for (int idx = tid; idx < m * C; idx += B) {
            int j = idx >> 3, c = idx & 7;
            w1s[j][c] = w1[eid[j] * C + c];
        }
        __syncthreads();
        for (int j = 0; j < m; ++j) {
            float xv = xe[eid[j] * B + tid];
            #pragma unroll
            for (int c = 0; c < C; ++c) acc[c] += xv * w1s[j][c];
        }
        __syncthreads();
    }
    #pragma unroll
    for (int c = 0; c < C; ++c) h[(n * C + c) * B + tid] = acc[c];
}

// partial sums (with +b1) for mean/var, per 64-row chunk
__global__ void k_stats(const float* __restrict__ h, const float* __restrict__ b1,
                        float* __restrict__ part) {
    int tid = threadIdx.x;
    int b = tid & 255, rg = tid >> 8;
    int r0 = blockIdx.x * SR;
    float s1 = 0.f, s2 = 0.f;
    for (int r = rg; r < SR; r += 4) {
        int i = r0 + r;
        float v = h[i * B + b] + b1[i];
        s1 += v; s2 += v * v;
    }
    __shared__ float l1[4][B], l2[4][B];
    l1[rg][b] = s1; l2[rg][b] = s2;
    __syncthreads();
    if (rg == 0) {
        float a = l1[0][b] + l1[1][b] + l1[2][b] + l1[3][b];
        float q = l2[0][b] + l2[1][b] + l2[2][b] + l2[3][b];
        part[blockIdx.x * (2 * B) + b]     = a;
        part[blockIdx.x * (2 * B) + B + b] = q;
    }
}

// in-place: h = elu( (h + b1 - mu) * rsqrt(var+eps) * gamma + beta )
__global__ void k_norm(float* __restrict__ h, const float* __restrict__ part,
                       const float* __restrict__ b1, const float* __restrict__ gamma,
                       const float* __restrict__ beta) {
    int tid = threadIdx.x;
    int b = tid & 255, rg = tid >> 8;
    float s1 = 0.f, s2 = 0.f;
    for (int k = rg; k < SB; k += 4) {
        s1 += part[k * (2 * B) + b];
        s2 += part[k * (2 * B) + B + b];
    }
    __shared__ float l1[4][B], l2[4][B], mu_s[B], rs_s[B];
    l1[rg][b] = s1; l2[rg][b] = s2;
    __syncthreads();
    if (rg == 0) {
        float S1 = l1[0][b] + l1[1][b] + l1[2][b] + l1[3][b];
        float S2 = l2[0][b] + l2[1][b] + l2[2][b] + l2[3][b];
        float mu = S1 * (1.0f / H);
        float var = S2 * (1.0f / H) - mu * mu;
        mu_s[b] = mu;
        rs_s[b] = rsqrtf(var + EPSF);
    }
    __syncthreads();
    float mu = mu_s[b], rs = rs_s[b];
    int r0 = blockIdx.x * SR;
    for (int r = rg; r < SR; r += 4) {
        int i = r0 + r;
        float v = h[i * B + b] + b1[i];
        v = (v - mu) * rs * gamma[i] + beta[i];
        h[i * B + b] = (v > 0.f) ? v : expm1f(v);
    }
}

// xe[e][b] += dot(hn[src], w2[e]) + b2[e]  (func src); xe += b2[e] (input src)
__global__ void k_edge(const float* __restrict__ h, const float* __restrict__ w2,
                       const float* __restrict__ b2, const int* __restrict__ rs_src,
                       const int* __restrict__ csr_src, float* __restrict__ xe) {
    int s = blockIdx.x, tid = threadIdx.x;
    int beg = rs_src[s], end = rs_src[s + 1];
    if (beg >= end) return;
    if (s < N_F) {
        float hv[C];
        #pragma unroll
        for (int c = 0; c < C; ++c) hv[c] = h[(s * C + c) * B + tid];
        __shared__ int   eid[CHK];
        __shared__ float w2s[CHK][C];
        __shared__ float b2s[CHK];
        for (int cb = beg; cb < end; cb += CHK) {
            int m = min(CHK, end - cb);
            if (tid < m) eid[tid] = csr_src[cb + tid];
            __syncthreads();
            for (int idx = tid; idx < m * C; idx += B) {
                int j = idx >> 3, c = idx & 7;
                w2s[j][c] = w2[eid[j] * C + c];
            }
            if (tid < m) b2s[tid] = b2[eid[tid]];
            __syncthreads();
            for (int j = 0; j < m; ++j) {
                float d = b2s[j];
                #pragma unroll
                for (int c = 0; c < C; ++c) d += hv[c] * w2s[j][c];
                xe[eid[j] * B + tid] += d;
            }
            __syncthreads();
        }
    } else {
        for (int j = beg; j < end; ++j) {
            int e = csr_src[j];
            xe[e * B + tid] += b2[e];
        }
    }
}

// out[b][n] = (n >= OUT0) ? sum_{e in csr_dst[n]} xe[e][b] / LAYERS : 0
__global__ void k_out(const float* __restrict__ xe, const int* __restrict__ rs_dst,
                      const int* __restrict__ csr_dst, float* __restrict__ out) {
    int n = blockIdx.x, b = threadIdx.x;
    float v = 0.f;
    if (n >= OUT0) {
        int beg = rs_dst[n], end = rs_dst[n + 1];
        for (int j = beg; j < end; ++j) v += xe[csr_dst[j] * B + b];
    }
    out[b * N_ALL + n] = v * (1.0f / LAYERS);
}

// ---------------- launch ----------------

extern "C" void kernel_launch(void* const* d_in, const int* in_sizes, int n_in,
                              void* d_out, int out_size, void* d_ws, size_t ws_size,
                              hipStream_t stream) {
    const float* x     = (const float*)d_in[0];
    const float* w1    = (const float*)d_in[1];
    const float* b1    = (const float*)d_in[2];
    const float* gamma = (const float*)d_in[3];
    const float* beta  = (const float*)d_in[4];
    const float* w2    = (const float*)d_in[5];
    const float* b2    = (const float*)d_in[6];
    const int*   ei    = (const int*)d_in[7];
    const int* src = ei;
    const int* dst = ei + E;
    float* out = (float*)d_out;

    char* p = (char*)d_ws;
    float* xe = (float*)p; p += (size_t)E * B * sizeof(float);
    float* xT = (float*)p; p += (size_t)N_ALL * B * sizeof(float);
    float* h  = (float*)p; p += (size_t)H * B * sizeof(float);
    float* part = (float*)p; p += (size_t)SB * 2 * B * sizeof(float);
    int* cnt_dst = (int*)p; p += N_ALL * sizeof(int);
    int* cnt_src = (int*)p; p += N_ALL * sizeof(int);
    int* rs_dst  = (int*)p; p += (N_ALL + 1) * sizeof(int);
    int* rs_src  = (int*)p; p += (N_ALL + 1) * sizeof(int);
    int* cur_dst = (int*)p; p += N_ALL * sizeof(int);
    int* cur_src = (int*)p; p += N_ALL * sizeof(int);
    int* csr_dst = (int*)p; p += E * sizeof(int);
    int* csr_src = (int*)p; p += E * sizeof(int);

    hipLaunchKernelGGL(k_zero,  dim3(1), dim3(1024), 0, stream, cnt_dst, cnt_src);
    hipLaunchKernelGGL(k_count, dim3((E + 255) / 256), dim3(256), 0, stream, src, dst, cnt_dst, cnt_src);
    hipLaunchKernelGGL(k_scan,  dim3(2), dim3(1024), 0, stream, cnt_dst, cnt_src, rs_dst, rs_src, cur_dst, cur_src);
    hipLaunchKernelGGL(k_fill,  dim3((E + 255) / 256), dim3(256), 0, stream, src, dst, cur_dst, cur_src, csr_dst, csr_src);
    hipLaunchKernelGGL(k_xT,    dim3((N_ALL + 31) / 32, B / 32), dim3(32, 32), 0, stream, x, xT);
    hipLaunchKernelGGL(k_init,  dim3((E + 15) / 16), dim3(256), 0, stream, src, xT, xe);

    for (int t = 0; t < LAYERS; ++t) {
        hipLaunchKernelGGL(k_hid,   dim3(N_F), dim3(256), 0, stream, xe, w1, rs_dst, csr_dst, h);
        hipLaunchKernelGGL(k_stats, dim3(SB), dim3(1024), 0, stream, h, b1, part);
        hipLaunchKernelGGL(k_norm,  dim3(SB), dim3(1024), 0, stream, h, part, b1, gamma, beta);
        hipLaunchKernelGGL(k_edge,  dim3(N_SRC), dim3(256), 0, stream, h, w2, b2, rs_src, csr_src, xe);
    }

    hipLaunchKernelGGL(k_out, dim3(N_ALL), dim3(256), 0, stream, xe, rs_dst, csr_dst, out);
}